// Round 9
// baseline (305.642 us; speedup 1.0000x reference)
//
#include <hip/hip_runtime.h>
#include <hip/hip_bf16.h>
#include <hip/hip_fp8.h>

#define N_NODES 200000
#define N_EDGES 1000000
#define NQ 64
#define NRELR 401
#define DIM 128
#define AA 64
#define NBK 3125  // 200000 / 64 exactly, buckets of 64 nodes
#define CAP 512   // max records staged per bucket (avg 320, >10 sigma headroom)

typedef __attribute__((ext_vector_type(8))) short short8_t;
typedef __attribute__((ext_vector_type(4))) float f32x4;

static __device__ inline short f2bs(float f) {
  __hip_bfloat16 h = __float2bfloat16(f);
  return __builtin_bit_cast(short, h);
}
static __device__ inline float bs2f(unsigned short u) {
  unsigned x = ((unsigned)u) << 16;
  return __builtin_bit_cast(float, x);
}
static __device__ inline unsigned pk2(float lo, float hi) {
  unsigned short a = (unsigned short)__builtin_bit_cast(short, __float2bfloat16(lo));
  unsigned short b = (unsigned short)__builtin_bit_cast(short, __float2bfloat16(hi));
  return (unsigned)a | ((unsigned)b << 16);
}
static __device__ inline unsigned char f2e4(float f) {
  __hip_fp8_e4m3 h(f);
  return (unsigned char)h.__x;
}
static __device__ inline float e42f(unsigned char b) {
  __hip_fp8_e4m3 h;
  h.__x = (__hip_fp8_storage_t)b;
  return (float)h;
}
static __device__ inline void atomic_pk_bf16_s(unsigned voff, unsigned val,
                                               const unsigned short* base) {
  asm volatile("global_atomic_pk_add_bf16 %0, %1, %2"
               :: "v"(voff), "v"(val), "s"((unsigned long long)base) : "memory");
}
static __device__ inline short8_t pack8(float4 a, float4 b) {
  short8_t v;
  v[0] = f2bs(a.x); v[1] = f2bs(a.y); v[2] = f2bs(a.z); v[3] = f2bs(a.w);
  v[4] = f2bs(b.x); v[5] = f2bs(b.y); v[6] = f2bs(b.z); v[7] = f2bs(b.w);
  return v;
}

// ============ fused PREP: [0,401)=C-role, [401,913)=S-role, [913,913+znum)=hist ============
#define CBK 401
#define SBK 512
__global__ __launch_bounds__(256) void prep_kernel(
    const float* __restrict__ hidden, const float* __restrict__ qemb,
    const float* __restrict__ rela, const float* __restrict__ Ws,
    const float* __restrict__ Wsb, const float* __restrict__ Wr,
    const float* __restrict__ Wq, const float* __restrict__ Wqr,
    const int* __restrict__ obj,
    unsigned char* __restrict__ C8, unsigned char* __restrict__ S8,
    unsigned short* __restrict__ relab, short* __restrict__ hidb,
    int* __restrict__ hist2d, int znum) {
  int b = blockIdx.x;
  int t = threadIdx.x;

  if (b < CBK) {
    __shared__ __hip_bfloat16 hqs[64][136];
    __shared__ __hip_bfloat16 vts[128][72];
    __shared__ float hr_f[128];
    __shared__ float trp[4][64];
    __shared__ float tr_s[64];
    int rho = b;

    if (t < 128) {
      float hv = rela[rho * DIM + t];
      hr_f[t] = hv;
      relab[rho * DIM + t] = (unsigned short)f2bs(hv);
    }
    __syncthreads();
    for (int i = t; i < 64 * 128; i += 256) {
      int q = i >> 7, d = i & 127;
      hqs[q][d] = __float2bfloat16(qemb[i]);
      int a = i >> 7;
      vts[d][a] = __float2bfloat16(Wq[i] + hr_f[d] * Wqr[i]);
    }
    {
      int a = t & 63, qt = t >> 6;
      const float* wr = Wr + a * DIM + qt * 32;
      float p = 0.f;
#pragma unroll 8
      for (int i = 0; i < 32; ++i) p += wr[i] * hr_f[qt * 32 + i];
      trp[qt][a] = p;
    }
    __syncthreads();
    if (t < 64)
      tr_s[t] = trp[0][t] + trp[1][t] + trp[2][t] + trp[3][t] + Wsb[t];
    __syncthreads();

    int qg = t >> 4, ag = t & 15;
    int q0 = qg * 4, a0 = ag * 4;
    float acc[4][4];
#pragma unroll
    for (int i = 0; i < 4; ++i)
#pragma unroll
      for (int j = 0; j < 4; ++j) acc[i][j] = 0.f;
    for (int d = 0; d < DIM; ++d) {
      float hv[4], wv[4];
#pragma unroll
      for (int i = 0; i < 4; ++i) hv[i] = __bfloat162float(hqs[q0 + i][d]);
#pragma unroll
      for (int j = 0; j < 4; ++j) wv[j] = __bfloat162float(vts[d][a0 + j]);
#pragma unroll
      for (int i = 0; i < 4; ++i)
#pragma unroll
        for (int j = 0; j < 4; ++j) acc[i][j] += hv[i] * wv[j];
    }
#pragma unroll
    for (int i = 0; i < 4; ++i)
#pragma unroll
      for (int j = 0; j < 4; ++j) {
        int q = q0 + i, a = a0 + j;
        C8[((size_t)rho * 64 + q) * 64 + a] = f2e4(acc[i][j] + tr_s[a]);
      }
  } else if (b < CBK + SBK) {
    int lane = t & 63;
    int lr = lane & 15, lg = lane >> 4;
    int gw = (b - CBK) * 4 + (t >> 6);
    const int NWV = SBK * 4;

    short8_t bf[4][4];
#pragma unroll
    for (int ot = 0; ot < 4; ++ot)
#pragma unroll
      for (int kt = 0; kt < 4; ++kt) {
        const float* wp = Ws + (size_t)(ot * 16 + lr) * DIM + kt * 32 + lg * 8;
        bf[ot][kt] = pack8(*(const float4*)wp, *(const float4*)(wp + 4));
      }

    for (int tt = gw; tt < N_NODES / 16; tt += NWV) {
      const float* ap = hidden + (size_t)tt * 16 * DIM + (size_t)lr * DIM;
      short8_t a[4];
#pragma unroll
      for (int kt = 0; kt < 4; ++kt) {
        const float* p = ap + kt * 32 + lg * 8;
        a[kt] = pack8(*(const float4*)p, *(const float4*)(p + 4));
        *(short8_t*)(hidb + ((size_t)tt * 16 + lr) * DIM + kt * 32 + lg * 8) = a[kt];
      }
      f32x4 acc[4];
#pragma unroll
      for (int ot = 0; ot < 4; ++ot) {
        acc[ot] = (f32x4){0.f, 0.f, 0.f, 0.f};
#pragma unroll
        for (int kt = 0; kt < 4; ++kt)
          acc[ot] = __builtin_amdgcn_mfma_f32_16x16x32_bf16(a[kt], bf[ot][kt], acc[ot], 0, 0, 0);
      }
#pragma unroll
      for (int ot = 0; ot < 4; ++ot)
#pragma unroll
        for (int r = 0; r < 4; ++r)
          S8[((size_t)tt * 16 + lg * 4 + r) * 64 + ot * 16 + lr] = f2e4(acc[ot][r]);
    }
  } else {
    // hist role: per-block private histogram of obj>>6, dumped to hist2d[z][*]
    __shared__ int h[NBK];
    int z = b - CBK - SBK;
    for (int i = t; i < NBK; i += 256) h[i] = 0;
    __syncthreads();
    for (int e = z * 256 + t; e < N_EDGES; e += znum * 256)
      atomicAdd(&h[obj[e] >> 6], 1);
    __syncthreads();
    for (int i = t; i < NBK; i += 256)
      hist2d[(size_t)z * NBK + i] = h[i];
  }
}

// ---------------- per-bucket scan across z: off2d + totals ----------------
__global__ __launch_bounds__(256) void offsetsA_kernel(
    const int* __restrict__ hist2d, int* __restrict__ off2d,
    int* __restrict__ totals, int znum) {
  int b0 = blockIdx.x * 256 + threadIdx.x;
  if (b0 >= NBK) return;
  int run = 0;
  for (int z = 0; z < znum; ++z) {
    int v = hist2d[(size_t)z * NBK + b0];
    off2d[(size_t)z * NBK + b0] = run;
    run += v;
  }
  totals[b0] = run;
}

// ---------------- exclusive scan over NBK totals (1 block) ----------------
__global__ __launch_bounds__(256) void scan_kernel(
    const int* __restrict__ totals, int* __restrict__ base) {
  __shared__ int part[256];
  int t = threadIdx.x;
  const int PER = (NBK + 255) / 256;  // 13
  int lo = t * PER;
  int loc[PER];
  int s = 0;
#pragma unroll
  for (int k = 0; k < PER; ++k) {
    loc[k] = s;
    int idx = lo + k;
    s += (idx < NBK) ? totals[idx] : 0;
  }
  part[t] = s;
  __syncthreads();
  for (int off = 1; off < 256; off <<= 1) {
    int v = (t >= off) ? part[t - off] : 0;
    __syncthreads();
    part[t] += v;
    __syncthreads();
  }
  int pre = (t == 0) ? 0 : part[t - 1];
#pragma unroll
  for (int k = 0; k < PER; ++k) {
    int idx = lo + k;
    if (idx < NBK) base[idx] = pre + loc[k];
  }
  if (t == 255) base[NBK] = part[255];
}

// ---------------- scatter3: precomputed offsets, zero global atomics ----------------
__global__ __launch_bounds__(256) void scatter3_kernel(
    const int* __restrict__ ridx, const int* __restrict__ rel,
    const int* __restrict__ sub, const int* __restrict__ obj,
    const int* __restrict__ base, const int* __restrict__ off2d,
    uint2* __restrict__ recs, int znum) {
  __shared__ int loff[NBK];
  __shared__ int lcur[NBK];
  int t = threadIdx.x, z = blockIdx.x;
  for (int i = t; i < NBK; i += 256) {
    loff[i] = base[i] + off2d[(size_t)z * NBK + i];
    lcur[i] = 0;
  }
  __syncthreads();
  for (int e = z * 256 + t; e < N_EDGES; e += znum * 256) {
    int s = sub[e], r = rel[e], q = ridx[e], o = obj[e];
    int bb = o >> 6;
    int rq = r * 64 + q;  // 15 bits
    int p = loff[bb] + atomicAdd(&lcur[bb], 1);
    uint2 rc;
    rc.x = (unsigned)s | ((unsigned)(o & 63) << 18) | ((unsigned)(rq & 0xFF) << 24);
    rc.y = (unsigned)(rq >> 8) | ((unsigned)e << 7);
    recs[p] = rc;
  }
}

// ---------------- bucket2: LDS counting-sort + per-wave node ownership ----------------
__global__ __launch_bounds__(256) void bucket2_kernel(
    const unsigned* __restrict__ hid32, const unsigned* __restrict__ rel32,
    const unsigned char* __restrict__ S8, const unsigned char* __restrict__ C8,
    const float* __restrict__ wal, const float* __restrict__ walb,
    const int* __restrict__ base, const uint2* __restrict__ recs,
    unsigned* __restrict__ agg32, float* __restrict__ alpha_out) {
  __shared__ uint2 lrec[CAP];          // 4 KB
  __shared__ unsigned short ord[CAP];  // 1 KB
  __shared__ int cnt2[64];
  __shared__ int scn[65];
  __shared__ int curs[64];
  int t = threadIdx.x, b = blockIdx.x;
  int lane = t & 63, w = t >> 6;
  int lo = base[b], hi = base[b + 1];
  int cnt = hi - lo;
  int nbase = b * 64;  // 3125*64 == 200000 exactly: no bounds checks
  float wa = wal[lane];
  float wb = walb[0];

  if (t < 64) cnt2[t] = 0;
  __syncthreads();

  if (cnt <= CAP) {
    for (int i = t; i < cnt; i += 256) {
      uint2 rc = recs[lo + i];
      lrec[i] = rc;
      atomicAdd(&cnt2[(rc.x >> 18) & 63], 1);
    }
    __syncthreads();
    if (t < 64) scn[t + 1] = cnt2[t];
    if (t == 0) scn[0] = 0;
    __syncthreads();
    for (int off = 1; off < 64; off <<= 1) {
      int v = 0;
      if (t < 64) { v = scn[t + 1]; if (t + 1 > off) v += scn[t + 1 - off]; }
      __syncthreads();
      if (t < 64) scn[t + 1] = v;
      __syncthreads();
    }
    if (t < 64) curs[t] = scn[t];
    __syncthreads();
    for (int i = t; i < cnt; i += 256) {
      int oin = (lrec[i].x >> 18) & 63;
      int p = atomicAdd(&curs[oin], 1);
      ord[p] = (unsigned short)i;
    }
    __syncthreads();

    // wave w owns nodes [w*16, w*16+16): run-length register accumulation
    int n0 = w * 16;
    int s0 = scn[n0], s1 = scn[n0 + 16];
    float m0 = 0.f, m1 = 0.f;
    int curn = -1;
    for (int j = s0; j < s1; j += 4) {
      int nv = s1 - j;
      if (nv > 4) nv = 4;
      int sdx[4], on[4], rq[4], ei[4];
      float y[4], h0[4], h1[4], g0[4], g1[4];
#pragma unroll
      for (int u = 0; u < 4; ++u) {
        int idx = (u < nv) ? (j + u) : j;
        uint2 rc = lrec[ord[idx]];
        unsigned rx = __builtin_amdgcn_readfirstlane(rc.x);
        unsigned ry = __builtin_amdgcn_readfirstlane(rc.y);
        sdx[u] = rx & 0x3FFFF;
        on[u] = (rx >> 18) & 63;
        rq[u] = ((rx >> 24) & 0xFF) | ((ry & 0x7F) << 8);
        ei[u] = ry >> 7;
      }
#pragma unroll
      for (int u = 0; u < 4; ++u) {
        float x = e42f(S8[(size_t)sdx[u] * 64 + lane]) +
                  e42f(C8[(size_t)rq[u] * 64 + lane]);
        y[u] = fmaxf(x, 0.f) * wa;
      }
#pragma unroll
      for (int u = 0; u < 4; ++u) {
        unsigned hp = hid32[(size_t)sdx[u] * 64 + lane];
        unsigned rp = rel32[(size_t)(rq[u] >> 6) * 64 + lane];
        h0[u] = bs2f((unsigned short)(hp & 0xffff));
        h1[u] = bs2f((unsigned short)(hp >> 16));
        g0[u] = bs2f((unsigned short)(rp & 0xffff));
        g1[u] = bs2f((unsigned short)(rp >> 16));
      }
#pragma unroll
      for (int off = 32; off; off >>= 1) {
#pragma unroll
        for (int u = 0; u < 4; ++u) y[u] += __shfl_xor(y[u], off);
      }
#pragma unroll
      for (int u = 0; u < 4; ++u) {
        if (u < nv) {
          float al = 1.f / (1.f + __expf(-(y[u] + wb)));
          if (on[u] != curn) {
            if (curn >= 0)
              agg32[(size_t)(nbase + curn) * 64 + lane] = pk2(m0, m1);
            curn = on[u];
            m0 = 0.f; m1 = 0.f;
          }
          m0 += al * h0[u] * g0[u];
          m1 += al * h1[u] * g1[u];
          if (lane == 0) alpha_out[ei[u]] = al;
        }
      }
    }
    if (curn >= 0)
      agg32[(size_t)(nbase + curn) * 64 + lane] = pk2(m0, m1);
    for (int n = n0; n < n0 + 16; ++n) {
      if (cnt2[n] == 0)
        agg32[(size_t)(nbase + n) * 64 + lane] = 0u;
    }
  } else {
    // overflow fallback (statistically impossible): zero rows, then pk atomics
    for (int n = w; n < 64; n += 4)
      agg32[(size_t)(nbase + n) * 64 + lane] = 0u;
    __syncthreads();
    unsigned voff = (unsigned)lane * 4;
    for (int i = lo + w * 4; i < hi; i += 16) {
      int nv = hi - i;
      if (nv > 4) nv = 4;
      for (int u = 0; u < 4; ++u) {
        if (u >= nv) break;
        uint2 rc = recs[i + u];
        unsigned rx = __builtin_amdgcn_readfirstlane(rc.x);
        unsigned ry = __builtin_amdgcn_readfirstlane(rc.y);
        int sdx = rx & 0x3FFFF;
        int on = (rx >> 18) & 63;
        int rq = ((rx >> 24) & 0xFF) | ((ry & 0x7F) << 8);
        int ei = ry >> 7;
        float x = e42f(S8[(size_t)sdx * 64 + lane]) + e42f(C8[(size_t)rq * 64 + lane]);
        float y = fmaxf(x, 0.f) * wa;
        for (int off = 32; off; off >>= 1) y += __shfl_xor(y, off);
        float al = 1.f / (1.f + __expf(-(y + wb)));
        unsigned hp = hid32[(size_t)sdx * 64 + lane];
        unsigned rp = rel32[(size_t)(rq >> 6) * 64 + lane];
        float v0 = al * bs2f((unsigned short)(hp & 0xffff)) * bs2f((unsigned short)(rp & 0xffff));
        float v1 = al * bs2f((unsigned short)(hp >> 16)) * bs2f((unsigned short)(rp >> 16));
        atomic_pk_bf16_s(voff, pk2(v0, v1), (const unsigned short*)(agg32 + (size_t)(nbase + on) * 64));
        if (lane == 0) alpha_out[ei] = al;
      }
    }
  }
}

// ---------------- out[n,o] = relu(sum_d aggbf[n,d]*Wh[o,d]) -> fp32 (MFMA) ----------------
__global__ __launch_bounds__(256) void out_gemm_bf(
    const float* __restrict__ Wh, const short* __restrict__ aggb,
    float* __restrict__ out) {
  int lane = threadIdx.x & 63;
  int lr = lane & 15, lg = lane >> 4;
  int gw = (blockIdx.x * blockDim.x + threadIdx.x) >> 6;
  int nwv = (gridDim.x * blockDim.x) >> 6;

  short8_t b[8][4];
#pragma unroll
  for (int ot = 0; ot < 8; ++ot)
#pragma unroll
    for (int kt = 0; kt < 4; ++kt) {
      const float* wp = Wh + (size_t)(ot * 16 + lr) * DIM + kt * 32 + lg * 8;
      b[ot][kt] = pack8(*(const float4*)wp, *(const float4*)(wp + 4));
    }

  for (int t = gw; t < N_NODES / 16; t += nwv) {
    const short* ap = aggb + ((size_t)t * 16 + lr) * DIM;
    short8_t a[4];
#pragma unroll
    for (int kt = 0; kt < 4; ++kt)
      a[kt] = *(const short8_t*)(ap + kt * 32 + lg * 8);
    f32x4 acc[8];
#pragma unroll
    for (int ot = 0; ot < 8; ++ot) {
      acc[ot] = (f32x4){0.f, 0.f, 0.f, 0.f};
#pragma unroll
      for (int kt = 0; kt < 4; ++kt)
        acc[ot] = __builtin_amdgcn_mfma_f32_16x16x32_bf16(a[kt], b[ot][kt], acc[ot], 0, 0, 0);
    }
    float* op = out + (size_t)t * 16 * DIM;
#pragma unroll
    for (int ot = 0; ot < 8; ++ot)
#pragma unroll
      for (int r = 0; r < 4; ++r)
        op[(size_t)(lg * 4 + r) * DIM + ot * 16 + lr] = fmaxf(acc[ot][r], 0.f);
  }
}

// ================= SMALL-ws fallback (round-2 proven path) =================
__global__ __launch_bounds__(256) void tq_kernel(
    const float* __restrict__ qemb, const float* __restrict__ Wq,
    float* __restrict__ Tq) {
  int t = blockIdx.x * 256 + threadIdx.x;
  if (t >= NQ * AA) return;
  int q = t >> 6, a = t & 63;
  float s = 0.f;
#pragma unroll 4
  for (int d = 0; d < DIM; ++d) s += qemb[q * DIM + d] * Wq[a * DIM + d];
  Tq[t] = s;
}

__global__ __launch_bounds__(256) void build_C_old(
    const float* __restrict__ qemb, const float* __restrict__ rela,
    const float* __restrict__ Wr, const float* __restrict__ Wqr,
    const float* __restrict__ Wsb, const float* __restrict__ Tq,
    __hip_bfloat16* __restrict__ Cout) {
  __shared__ float hrq[64 * 129];
  __shared__ float wqrT[128 * 65];
  __shared__ float wrT[128 * 65];
  __shared__ float hr_s[128];
  __shared__ float tr_s[64];
  int rho = blockIdx.x;
  int t = threadIdx.x;
  if (t < 128) hr_s[t] = rela[rho * DIM + t];
  __syncthreads();
  for (int i = t; i < 64 * 128; i += 256) {
    int a = i >> 7, d = i & 127;
    hrq[a * 129 + d] = qemb[i] * hr_s[d];
    wqrT[d * 65 + a] = Wqr[i];
    wrT[d * 65 + a] = Wr[i];
  }
  __syncthreads();
  if (t < 64) {
    float s = 0.f;
#pragma unroll 4
    for (int d = 0; d < DIM; ++d) s += wrT[d * 65 + t] * hr_s[d];
    tr_s[t] = s + Wsb[t];
  }
  __syncthreads();
  int qg = t >> 4, ag = t & 15;
  int q0 = qg * 4, a0 = ag * 4;
  float acc[4][4];
#pragma unroll
  for (int i = 0; i < 4; ++i)
#pragma unroll
    for (int j = 0; j < 4; ++j) acc[i][j] = 0.f;
  for (int d = 0; d < DIM; ++d) {
    float hv[4], wv[4];
#pragma unroll
    for (int i = 0; i < 4; ++i) hv[i] = hrq[(q0 + i) * 129 + d];
#pragma unroll
    for (int j = 0; j < 4; ++j) wv[j] = wqrT[d * 65 + a0 + j];
#pragma unroll
    for (int i = 0; i < 4; ++i)
#pragma unroll
      for (int j = 0; j < 4; ++j) acc[i][j] += hv[i] * wv[j];
  }
#pragma unroll
  for (int i = 0; i < 4; ++i)
#pragma unroll
    for (int j = 0; j < 4; ++j) {
      int q = q0 + i, a = a0 + j;
      Cout[(rho * 64 + q) * 64 + a] = __float2bfloat16(acc[i][j] + Tq[q * 64 + a] + tr_s[a]);
    }
}

__global__ __launch_bounds__(256) void build_S_old(
    const float* __restrict__ hidden, const float* __restrict__ Ws,
    __hip_bfloat16* __restrict__ Sout) {
  int lane = threadIdx.x & 63;
  int lr = lane & 15, lg = lane >> 4;
  int gw = (blockIdx.x * blockDim.x + threadIdx.x) >> 6;
  int nwv = (gridDim.x * blockDim.x) >> 6;
  short8_t b[4][4];
#pragma unroll
  for (int ot = 0; ot < 4; ++ot)
#pragma unroll
    for (int kt = 0; kt < 4; ++kt) {
      const float* wp = Ws + (size_t)(ot * 16 + lr) * DIM + kt * 32 + lg * 8;
      b[ot][kt] = pack8(*(const float4*)wp, *(const float4*)(wp + 4));
    }
  for (int t = gw; t < N_NODES / 16; t += nwv) {
    const float* ap = hidden + (size_t)t * 16 * DIM + (size_t)lr * DIM;
    short8_t a[4];
#pragma unroll
    for (int kt = 0; kt < 4; ++kt) {
      const float* p = ap + kt * 32 + lg * 8;
      a[kt] = pack8(*(const float4*)p, *(const float4*)(p + 4));
    }
    f32x4 acc[4];
#pragma unroll
    for (int ot = 0; ot < 4; ++ot) {
      acc[ot] = (f32x4){0.f, 0.f, 0.f, 0.f};
#pragma unroll
      for (int kt = 0; kt < 4; ++kt)
        acc[ot] = __builtin_amdgcn_mfma_f32_16x16x32_bf16(a[kt], b[ot][kt], acc[ot], 0, 0, 0);
    }
#pragma unroll
    for (int ot = 0; ot < 4; ++ot)
#pragma unroll
      for (int r = 0; r < 4; ++r)
        Sout[((size_t)t * 16 + lg * 4 + r) * 64 + ot * 16 + lr] = __float2bfloat16(acc[ot][r]);
  }
}

__global__ __launch_bounds__(256) void edge_kernel_old(
    const float* __restrict__ hidden, const float* __restrict__ rela,
    const __hip_bfloat16* __restrict__ S, const __hip_bfloat16* __restrict__ C,
    const float* __restrict__ wal, const float* __restrict__ walb,
    const int* __restrict__ ridx, const int* __restrict__ rel,
    const int* __restrict__ sub, const int* __restrict__ obj,
    float* __restrict__ agg, float* __restrict__ alpha_out) {
  int lane = threadIdx.x & 63;
  int wid = (blockIdx.x * blockDim.x + threadIdx.x) >> 6;
  const int CH = 124;
  int e0 = wid * CH;
  if (e0 >= N_EDGES) return;
  int e1 = e0 + CH;
  if (e1 > N_EDGES) e1 = N_EDGES;
  float wa = wal[lane];
  float wb = walb[0];
  for (int e = e0; e < e1; e += 4) {
    int4 ss = *(const int4*)(sub + e);
    int4 rr = *(const int4*)(rel + e);
    int4 qq = *(const int4*)(ridx + e);
    int4 oo = *(const int4*)(obj + e);
    int s[4] = {ss.x, ss.y, ss.z, ss.w};
    int r[4] = {rr.x, rr.y, rr.z, rr.w};
    int q[4] = {qq.x, qq.y, qq.z, qq.w};
    int o[4] = {oo.x, oo.y, oo.z, oo.w};
    float y[4];
#pragma unroll
    for (int u = 0; u < 4; ++u) {
      float x = __bfloat162float(S[(size_t)s[u] * 64 + lane]) +
                __bfloat162float(C[((size_t)r[u] * 64 + q[u]) * 64 + lane]);
      y[u] = fmaxf(x, 0.f) * wa;
    }
    float h0[4], h1[4], r0[4], r1[4];
#pragma unroll
    for (int u = 0; u < 4; ++u) {
      h0[u] = hidden[(size_t)s[u] * DIM + lane];
      h1[u] = hidden[(size_t)s[u] * DIM + 64 + lane];
      r0[u] = rela[(size_t)r[u] * DIM + lane];
      r1[u] = rela[(size_t)r[u] * DIM + 64 + lane];
    }
#pragma unroll
    for (int off = 32; off; off >>= 1) {
#pragma unroll
      for (int u = 0; u < 4; ++u) y[u] += __shfl_xor(y[u], off);
    }
    float al[4];
#pragma unroll
    for (int u = 0; u < 4; ++u) al[u] = 1.f / (1.f + __expf(-(y[u] + wb)));
#pragma unroll
    for (int u = 0; u < 4; ++u) {
      unsafeAtomicAdd(&agg[(size_t)o[u] * DIM + lane], al[u] * h0[u] * r0[u]);
      unsafeAtomicAdd(&agg[(size_t)o[u] * DIM + 64 + lane], al[u] * h1[u] * r1[u]);
    }
    if (lane == 0)
      *(float4*)(alpha_out + e) = make_float4(al[0], al[1], al[2], al[3]);
  }
}

__global__ __launch_bounds__(256) void out_gemm_old(
    const float* __restrict__ Wh, float* __restrict__ agg) {
  int lane = threadIdx.x & 63;
  int lr = lane & 15, lg = lane >> 4;
  int gw = (blockIdx.x * blockDim.x + threadIdx.x) >> 6;
  int nwv = (gridDim.x * blockDim.x) >> 6;
  short8_t b[8][4];
#pragma unroll
  for (int ot = 0; ot < 8; ++ot)
#pragma unroll
    for (int kt = 0; kt < 4; ++kt) {
      const float* wp = Wh + (size_t)(ot * 16 + lr) * DIM + kt * 32 + lg * 8;
      b[ot][kt] = pack8(*(const float4*)wp, *(const float4*)(wp + 4));
    }
  for (int t = gw; t < N_NODES / 16; t += nwv) {
    float* ap = agg + (size_t)t * 16 * DIM + (size_t)lr * DIM;
    short8_t a[4];
#pragma unroll
    for (int kt = 0; kt < 4; ++kt) {
      const float* p = ap + kt * 32 + lg * 8;
      a[kt] = pack8(*(const float4*)p, *(const float4*)(p + 4));
    }
    f32x4 acc[8];
#pragma unroll
    for (int ot = 0; ot < 8; ++ot) {
      acc[ot] = (f32x4){0.f, 0.f, 0.f, 0.f};
#pragma unroll
      for (int kt = 0; kt < 4; ++kt)
        acc[ot] = __builtin_amdgcn_mfma_f32_16x16x32_bf16(a[kt], b[ot][kt], acc[ot], 0, 0, 0);
    }
    float* op = agg + (size_t)t * 16 * DIM;
#pragma unroll
    for (int ot = 0; ot < 8; ++ot)
#pragma unroll
      for (int r = 0; r < 4; ++r)
        op[(size_t)(lg * 4 + r) * DIM + ot * 16 + lr] = fmaxf(acc[ot][r], 0.f);
  }
}

extern "C" void kernel_launch(void* const* d_in, const int* in_sizes, int n_in,
                              void* d_out, int out_size, void* d_ws, size_t ws_size,
                              hipStream_t stream) {
  const float* hidden = (const float*)d_in[0];
  const float* qemb   = (const float*)d_in[1];
  const float* rela   = (const float*)d_in[2];
  const float* Ws_w   = (const float*)d_in[3];
  const float* Ws_b   = (const float*)d_in[4];
  const float* Wr_w   = (const float*)d_in[5];
  const float* Wq_w   = (const float*)d_in[6];
  const float* Wqr_w  = (const float*)d_in[7];
  const float* wal_w  = (const float*)d_in[8];
  const float* wal_b  = (const float*)d_in[9];
  const float* Wh_w   = (const float*)d_in[10];
  const int* r_idx    = (const int*)d_in[11];
  const int* rel      = (const int*)d_in[12];
  const int* sub      = (const int*)d_in[13];
  const int* obj      = (const int*)d_in[14];

  float* out_hidden = (float*)d_out;
  float* out_alpha  = out_hidden + (size_t)N_NODES * DIM;

  char* ws = (char*)d_ws;
  const size_t OFF_C8  = 0;
  const size_t SZ_C8   = (size_t)NRELR * 64 * 64;     // 1,642,496
  const size_t OFF_S8  = OFF_C8 + SZ_C8;
  const size_t SZ_S8   = (size_t)N_NODES * 64;        // 12,800,000
  const size_t OFF_RB  = OFF_S8 + SZ_S8;              // 14,442,496
  const size_t SZ_RB   = (size_t)NRELR * DIM * 2;     // 102,656
  const size_t OFF_HB  = OFF_RB + SZ_RB;              // 14,545,152
  const size_t SZ_HB   = (size_t)N_NODES * DIM * 2;   // 51,200,000
  const size_t OFF_AG  = OFF_HB + SZ_HB;              // 65,745,152
  const size_t OFF_H2D = OFF_AG + SZ_HB;              // 116,945,152

  // choose znum tier by available ws
  int znum = 0;
  size_t off_o2d = 0, off_tot = 0, off_base = 0, off_rec = 0;
  for (int zc = 256; zc >= 128; zc >>= 1) {
    size_t szh = (size_t)zc * NBK * 4;
    size_t o2d = OFF_H2D + szh;
    size_t tot = o2d + szh;
    size_t bas = tot + 16384;
    size_t rec = bas + 16384;
    size_t need = rec + (size_t)N_EDGES * 8;
    if (ws_size >= need) {
      znum = zc; off_o2d = o2d; off_tot = tot; off_base = bas; off_rec = rec;
      break;
    }
  }

  if (znum) {
    unsigned char* C8 = (unsigned char*)(ws + OFF_C8);
    unsigned char* S8 = (unsigned char*)(ws + OFF_S8);
    unsigned short* relab = (unsigned short*)(ws + OFF_RB);
    short* hidb = (short*)(ws + OFF_HB);
    unsigned short* aggb = (unsigned short*)(ws + OFF_AG);
    int* hist2d = (int*)(ws + OFF_H2D);
    int* off2d  = (int*)(ws + off_o2d);
    int* totals = (int*)(ws + off_tot);
    int* base   = (int*)(ws + off_base);
    uint2* recs = (uint2*)(ws + off_rec);

    prep_kernel<<<CBK + SBK + znum, 256, 0, stream>>>(
        hidden, qemb, rela, Ws_w, Ws_b, Wr_w, Wq_w, Wqr_w, obj,
        C8, S8, relab, hidb, hist2d, znum);
    offsetsA_kernel<<<(NBK + 255) / 256, 256, 0, stream>>>(hist2d, off2d, totals, znum);
    scan_kernel<<<1, 256, 0, stream>>>(totals, base);
    scatter3_kernel<<<znum, 256, 0, stream>>>(r_idx, rel, sub, obj, base, off2d, recs, znum);
    bucket2_kernel<<<NBK, 256, 0, stream>>>(
        (const unsigned*)hidb, (const unsigned*)relab, S8, C8,
        wal_w, wal_b, base, recs, (unsigned*)aggb, out_alpha);
    out_gemm_bf<<<512, 256, 0, stream>>>(Wh_w, (const short*)aggb, out_hidden);
  } else {
    // SMALL fallback: round-2 proven path (28.9 MB)
    const size_t OFF_CBo = 16384;
    const size_t SZ_CBo  = (size_t)NRELR * 64 * 64 * 2;
    const size_t OFF_SBo = OFF_CBo + SZ_CBo;
    float* Tq = (float*)ws;
    __hip_bfloat16* Cb = (__hip_bfloat16*)(ws + OFF_CBo);
    __hip_bfloat16* Sb = (__hip_bfloat16*)(ws + OFF_SBo);
    hipMemsetAsync(out_hidden, 0, (size_t)N_NODES * DIM * sizeof(float), stream);
    tq_kernel<<<16, 256, 0, stream>>>(qemb, Wq_w, Tq);
    build_C_old<<<NRELR, 256, 0, stream>>>(qemb, rela, Wr_w, Wqr_w, Ws_b, Tq, Cb);
    build_S_old<<<512, 256, 0, stream>>>(hidden, Ws_w, Sb);
    edge_kernel_old<<<2048, 256, 0, stream>>>(hidden, rela, Sb, Cb, wal_w, wal_b,
                                              r_idx, rel, sub, obj, out_hidden, out_alpha);
    out_gemm_old<<<512, 256, 0, stream>>>(Wh_w, out_hidden);
  }
}

// Round 10
// 255.255 us; speedup vs baseline: 1.1974x; 1.1974x over previous
//
#include <hip/hip_runtime.h>
#include <hip/hip_bf16.h>
#include <hip/hip_fp8.h>

#define N_NODES 200000
#define N_EDGES 1000000
#define NQ 64
#define NRELR 401
#define DIM 128
#define AA 64
#define NBK 3125  // 200000 / 64 exactly, buckets of 64 nodes
#define CAP 512   // max records staged per bucket (avg 320, >10 sigma headroom)

typedef __attribute__((ext_vector_type(8))) short short8_t;
typedef __attribute__((ext_vector_type(4))) float f32x4;

static __device__ inline short f2bs(float f) {
  __hip_bfloat16 h = __float2bfloat16(f);
  return __builtin_bit_cast(short, h);
}
static __device__ inline float bs2f(unsigned short u) {
  unsigned x = ((unsigned)u) << 16;
  return __builtin_bit_cast(float, x);
}
static __device__ inline unsigned pk2(float lo, float hi) {
  unsigned short a = (unsigned short)__builtin_bit_cast(short, __float2bfloat16(lo));
  unsigned short b = (unsigned short)__builtin_bit_cast(short, __float2bfloat16(hi));
  return (unsigned)a | ((unsigned)b << 16);
}
static __device__ inline unsigned char f2e4(float f) {
  __hip_fp8_e4m3 h(f);
  return (unsigned char)h.__x;
}
static __device__ inline float e42f(unsigned char b) {
  __hip_fp8_e4m3 h;
  h.__x = (__hip_fp8_storage_t)b;
  return (float)h;
}
static __device__ inline void atomic_pk_bf16_s(unsigned voff, unsigned val,
                                               const unsigned short* base) {
  asm volatile("global_atomic_pk_add_bf16 %0, %1, %2"
               :: "v"(voff), "v"(val), "s"((unsigned long long)base) : "memory");
}
static __device__ inline short8_t pack8(float4 a, float4 b) {
  short8_t v;
  v[0] = f2bs(a.x); v[1] = f2bs(a.y); v[2] = f2bs(a.z); v[3] = f2bs(a.w);
  v[4] = f2bs(b.x); v[5] = f2bs(b.y); v[6] = f2bs(b.z); v[7] = f2bs(b.w);
  return v;
}

// ============ fused PREP: [0,401)=C-role, [401,913)=S-role, [913,913+znum)=hist ============
#define CBK 401
#define SBK 512
__global__ __launch_bounds__(256) void prep_kernel(
    const float* __restrict__ hidden, const float* __restrict__ qemb,
    const float* __restrict__ rela, const float* __restrict__ Ws,
    const float* __restrict__ Wsb, const float* __restrict__ Wr,
    const float* __restrict__ Wq, const float* __restrict__ Wqr,
    const int* __restrict__ obj,
    unsigned char* __restrict__ C8, unsigned char* __restrict__ S8,
    unsigned short* __restrict__ relab, short* __restrict__ hidb,
    int* __restrict__ hist2d, int znum) {
  int b = blockIdx.x;
  int t = threadIdx.x;

  if (b < CBK) {
    __shared__ __hip_bfloat16 hqs[64][136];
    __shared__ __hip_bfloat16 vts[128][72];
    __shared__ float hr_f[128];
    __shared__ float trp[4][64];
    __shared__ float tr_s[64];
    int rho = b;

    if (t < 128) {
      float hv = rela[rho * DIM + t];
      hr_f[t] = hv;
      relab[rho * DIM + t] = (unsigned short)f2bs(hv);
    }
    __syncthreads();
    for (int i = t; i < 64 * 128; i += 256) {
      int q = i >> 7, d = i & 127;
      hqs[q][d] = __float2bfloat16(qemb[i]);
      int a = i >> 7;
      vts[d][a] = __float2bfloat16(Wq[i] + hr_f[d] * Wqr[i]);
    }
    {
      int a = t & 63, qt = t >> 6;
      const float* wr = Wr + a * DIM + qt * 32;
      float p = 0.f;
#pragma unroll 8
      for (int i = 0; i < 32; ++i) p += wr[i] * hr_f[qt * 32 + i];
      trp[qt][a] = p;
    }
    __syncthreads();
    if (t < 64)
      tr_s[t] = trp[0][t] + trp[1][t] + trp[2][t] + trp[3][t] + Wsb[t];
    __syncthreads();

    int qg = t >> 4, ag = t & 15;
    int q0 = qg * 4, a0 = ag * 4;
    float acc[4][4];
#pragma unroll
    for (int i = 0; i < 4; ++i)
#pragma unroll
      for (int j = 0; j < 4; ++j) acc[i][j] = 0.f;
    for (int d = 0; d < DIM; ++d) {
      float hv[4], wv[4];
#pragma unroll
      for (int i = 0; i < 4; ++i) hv[i] = __bfloat162float(hqs[q0 + i][d]);
#pragma unroll
      for (int j = 0; j < 4; ++j) wv[j] = __bfloat162float(vts[d][a0 + j]);
#pragma unroll
      for (int i = 0; i < 4; ++i)
#pragma unroll
        for (int j = 0; j < 4; ++j) acc[i][j] += hv[i] * wv[j];
    }
#pragma unroll
    for (int i = 0; i < 4; ++i)
#pragma unroll
      for (int j = 0; j < 4; ++j) {
        int q = q0 + i, a = a0 + j;
        C8[((size_t)rho * 64 + q) * 64 + a] = f2e4(acc[i][j] + tr_s[a]);
      }
  } else if (b < CBK + SBK) {
    int lane = t & 63;
    int lr = lane & 15, lg = lane >> 4;
    int gw = (b - CBK) * 4 + (t >> 6);
    const int NWV = SBK * 4;

    short8_t bf[4][4];
#pragma unroll
    for (int ot = 0; ot < 4; ++ot)
#pragma unroll
      for (int kt = 0; kt < 4; ++kt) {
        const float* wp = Ws + (size_t)(ot * 16 + lr) * DIM + kt * 32 + lg * 8;
        bf[ot][kt] = pack8(*(const float4*)wp, *(const float4*)(wp + 4));
      }

    for (int tt = gw; tt < N_NODES / 16; tt += NWV) {
      const float* ap = hidden + (size_t)tt * 16 * DIM + (size_t)lr * DIM;
      short8_t a[4];
#pragma unroll
      for (int kt = 0; kt < 4; ++kt) {
        const float* p = ap + kt * 32 + lg * 8;
        a[kt] = pack8(*(const float4*)p, *(const float4*)(p + 4));
        *(short8_t*)(hidb + ((size_t)tt * 16 + lr) * DIM + kt * 32 + lg * 8) = a[kt];
      }
      f32x4 acc[4];
#pragma unroll
      for (int ot = 0; ot < 4; ++ot) {
        acc[ot] = (f32x4){0.f, 0.f, 0.f, 0.f};
#pragma unroll
        for (int kt = 0; kt < 4; ++kt)
          acc[ot] = __builtin_amdgcn_mfma_f32_16x16x32_bf16(a[kt], bf[ot][kt], acc[ot], 0, 0, 0);
      }
#pragma unroll
      for (int ot = 0; ot < 4; ++ot)
#pragma unroll
        for (int r = 0; r < 4; ++r)
          S8[((size_t)tt * 16 + lg * 4 + r) * 64 + ot * 16 + lr] = f2e4(acc[ot][r]);
    }
  } else {
    // hist role: per-block private histogram of obj>>6, dumped to hist2d[z][*]
    __shared__ int h[NBK];
    int z = b - CBK - SBK;
    for (int i = t; i < NBK; i += 256) h[i] = 0;
    __syncthreads();
    for (int e = z * 256 + t; e < N_EDGES; e += znum * 256)
      atomicAdd(&h[obj[e] >> 6], 1);
    __syncthreads();
    for (int i = t; i < NBK; i += 256)
      hist2d[(size_t)z * NBK + i] = h[i];
  }
}

// ---------------- wave-parallel per-bucket scan across z: off2d + totals ----------------
__global__ __launch_bounds__(256) void offsetsB_kernel(
    const int* __restrict__ hist2d, int* __restrict__ off2d,
    int* __restrict__ totals, int znum) {
  int t = threadIdx.x;
  int lane = t & 63, w = t >> 6;
  int b = blockIdx.x * 4 + w;
  if (b >= NBK) return;
  int n = znum >> 6;  // values per lane: 4 (znum=256) or 2 (znum=128)
  int v[4], loc[4];
  int s = 0;
#pragma unroll 4
  for (int j = 0; j < 4; ++j) {
    if (j < n) {
      v[j] = hist2d[(size_t)(lane * n + j) * NBK + b];
      loc[j] = s;
      s += v[j];
    }
  }
  // inclusive shuffle scan over 64 lanes
  int x = s;
#pragma unroll
  for (int off = 1; off < 64; off <<= 1) {
    int y = __shfl_up(x, off);
    if (lane >= off) x += y;
  }
  int excl = x - s;
#pragma unroll 4
  for (int j = 0; j < 4; ++j) {
    if (j < n)
      off2d[(size_t)(lane * n + j) * NBK + b] = excl + loc[j];
  }
  if (lane == 63) totals[b] = x;
}

// ---------------- exclusive scan over NBK totals (1 block) ----------------
__global__ __launch_bounds__(256) void scan_kernel(
    const int* __restrict__ totals, int* __restrict__ base) {
  __shared__ int part[256];
  int t = threadIdx.x;
  const int PER = (NBK + 255) / 256;  // 13
  int lo = t * PER;
  int loc[PER];
  int s = 0;
#pragma unroll
  for (int k = 0; k < PER; ++k) {
    loc[k] = s;
    int idx = lo + k;
    s += (idx < NBK) ? totals[idx] : 0;
  }
  part[t] = s;
  __syncthreads();
  for (int off = 1; off < 256; off <<= 1) {
    int v = (t >= off) ? part[t - off] : 0;
    __syncthreads();
    part[t] += v;
    __syncthreads();
  }
  int pre = (t == 0) ? 0 : part[t - 1];
#pragma unroll
  for (int k = 0; k < PER; ++k) {
    int idx = lo + k;
    if (idx < NBK) base[idx] = pre + loc[k];
  }
  if (t == 255) base[NBK] = part[255];
}

// ---------------- scatter3: precomputed offsets, zero global atomics ----------------
__global__ __launch_bounds__(256) void scatter3_kernel(
    const int* __restrict__ ridx, const int* __restrict__ rel,
    const int* __restrict__ sub, const int* __restrict__ obj,
    const int* __restrict__ base, const int* __restrict__ off2d,
    uint2* __restrict__ recs, int znum) {
  __shared__ int loff[NBK];
  __shared__ int lcur[NBK];
  int t = threadIdx.x, z = blockIdx.x;
  for (int i = t; i < NBK; i += 256) {
    loff[i] = base[i] + off2d[(size_t)z * NBK + i];
    lcur[i] = 0;
  }
  __syncthreads();
  for (int e = z * 256 + t; e < N_EDGES; e += znum * 256) {
    int s = sub[e], r = rel[e], q = ridx[e], o = obj[e];
    int bb = o >> 6;
    int rq = r * 64 + q;  // 15 bits
    int p = loff[bb] + atomicAdd(&lcur[bb], 1);
    uint2 rc;
    rc.x = (unsigned)s | ((unsigned)(o & 63) << 18) | ((unsigned)(rq & 0xFF) << 24);
    rc.y = (unsigned)(rq >> 8) | ((unsigned)e << 7);
    recs[p] = rc;
  }
}

// ---------------- bucket2: LDS counting-sort + per-wave node ownership ----------------
__global__ __launch_bounds__(256) void bucket2_kernel(
    const unsigned* __restrict__ hid32, const unsigned* __restrict__ rel32,
    const unsigned char* __restrict__ S8, const unsigned char* __restrict__ C8,
    const float* __restrict__ wal, const float* __restrict__ walb,
    const int* __restrict__ base, const uint2* __restrict__ recs,
    unsigned* __restrict__ agg32, float* __restrict__ alpha_out) {
  __shared__ uint2 lrec[CAP];          // 4 KB
  __shared__ unsigned short ord[CAP];  // 1 KB
  __shared__ int cnt2[64];
  __shared__ int scn[65];
  __shared__ int curs[64];
  int t = threadIdx.x, b = blockIdx.x;
  int lane = t & 63, w = t >> 6;
  int lo = base[b], hi = base[b + 1];
  int cnt = hi - lo;
  int nbase = b * 64;  // 3125*64 == 200000 exactly: no bounds checks
  float wa = wal[lane];
  float wb = walb[0];

  if (t < 64) cnt2[t] = 0;
  __syncthreads();

  if (cnt <= CAP) {
    for (int i = t; i < cnt; i += 256) {
      uint2 rc = recs[lo + i];
      lrec[i] = rc;
      atomicAdd(&cnt2[(rc.x >> 18) & 63], 1);
    }
    __syncthreads();
    if (t < 64) scn[t + 1] = cnt2[t];
    if (t == 0) scn[0] = 0;
    __syncthreads();
    for (int off = 1; off < 64; off <<= 1) {
      int v = 0;
      if (t < 64) { v = scn[t + 1]; if (t + 1 > off) v += scn[t + 1 - off]; }
      __syncthreads();
      if (t < 64) scn[t + 1] = v;
      __syncthreads();
    }
    if (t < 64) curs[t] = scn[t];
    __syncthreads();
    for (int i = t; i < cnt; i += 256) {
      int oin = (lrec[i].x >> 18) & 63;
      int p = atomicAdd(&curs[oin], 1);
      ord[p] = (unsigned short)i;
    }
    __syncthreads();

    // wave w owns nodes [w*16, w*16+16): run-length register accumulation
    int n0 = w * 16;
    int s0 = scn[n0], s1 = scn[n0 + 16];
    float m0 = 0.f, m1 = 0.f;
    int curn = -1;
    for (int j = s0; j < s1; j += 4) {
      int nv = s1 - j;
      if (nv > 4) nv = 4;
      int sdx[4], on[4], rq[4], ei[4];
      float y[4], h0[4], h1[4], g0[4], g1[4];
#pragma unroll
      for (int u = 0; u < 4; ++u) {
        int idx = (u < nv) ? (j + u) : j;
        uint2 rc = lrec[ord[idx]];
        unsigned rx = __builtin_amdgcn_readfirstlane(rc.x);
        unsigned ry = __builtin_amdgcn_readfirstlane(rc.y);
        sdx[u] = rx & 0x3FFFF;
        on[u] = (rx >> 18) & 63;
        rq[u] = ((rx >> 24) & 0xFF) | ((ry & 0x7F) << 8);
        ei[u] = ry >> 7;
      }
#pragma unroll
      for (int u = 0; u < 4; ++u) {
        float x = e42f(S8[(size_t)sdx[u] * 64 + lane]) +
                  e42f(C8[(size_t)rq[u] * 64 + lane]);
        y[u] = fmaxf(x, 0.f) * wa;
      }
#pragma unroll
      for (int u = 0; u < 4; ++u) {
        unsigned hp = hid32[(size_t)sdx[u] * 64 + lane];
        unsigned rp = rel32[(size_t)(rq[u] >> 6) * 64 + lane];
        h0[u] = bs2f((unsigned short)(hp & 0xffff));
        h1[u] = bs2f((unsigned short)(hp >> 16));
        g0[u] = bs2f((unsigned short)(rp & 0xffff));
        g1[u] = bs2f((unsigned short)(rp >> 16));
      }
#pragma unroll
      for (int off = 32; off; off >>= 1) {
#pragma unroll
        for (int u = 0; u < 4; ++u) y[u] += __shfl_xor(y[u], off);
      }
#pragma unroll
      for (int u = 0; u < 4; ++u) {
        if (u < nv) {
          float al = 1.f / (1.f + __expf(-(y[u] + wb)));
          if (on[u] != curn) {
            if (curn >= 0)
              agg32[(size_t)(nbase + curn) * 64 + lane] = pk2(m0, m1);
            curn = on[u];
            m0 = 0.f; m1 = 0.f;
          }
          m0 += al * h0[u] * g0[u];
          m1 += al * h1[u] * g1[u];
          if (lane == 0) alpha_out[ei[u]] = al;
        }
      }
    }
    if (curn >= 0)
      agg32[(size_t)(nbase + curn) * 64 + lane] = pk2(m0, m1);
    for (int n = n0; n < n0 + 16; ++n) {
      if (cnt2[n] == 0)
        agg32[(size_t)(nbase + n) * 64 + lane] = 0u;
    }
  } else {
    // overflow fallback (statistically impossible): zero rows, then pk atomics
    for (int n = w; n < 64; n += 4)
      agg32[(size_t)(nbase + n) * 64 + lane] = 0u;
    __syncthreads();
    unsigned voff = (unsigned)lane * 4;
    for (int i = lo + w * 4; i < hi; i += 16) {
      int nv = hi - i;
      if (nv > 4) nv = 4;
      for (int u = 0; u < 4; ++u) {
        if (u >= nv) break;
        uint2 rc = recs[i + u];
        unsigned rx = __builtin_amdgcn_readfirstlane(rc.x);
        unsigned ry = __builtin_amdgcn_readfirstlane(rc.y);
        int sdx = rx & 0x3FFFF;
        int on = (rx >> 18) & 63;
        int rq = ((rx >> 24) & 0xFF) | ((ry & 0x7F) << 8);
        int ei = ry >> 7;
        float x = e42f(S8[(size_t)sdx * 64 + lane]) + e42f(C8[(size_t)rq * 64 + lane]);
        float y = fmaxf(x, 0.f) * wa;
        for (int off = 32; off; off >>= 1) y += __shfl_xor(y, off);
        float al = 1.f / (1.f + __expf(-(y + wb)));
        unsigned hp = hid32[(size_t)sdx * 64 + lane];
        unsigned rp = rel32[(size_t)(rq >> 6) * 64 + lane];
        float v0 = al * bs2f((unsigned short)(hp & 0xffff)) * bs2f((unsigned short)(rp & 0xffff));
        float v1 = al * bs2f((unsigned short)(hp >> 16)) * bs2f((unsigned short)(rp >> 16));
        atomic_pk_bf16_s(voff, pk2(v0, v1), (const unsigned short*)(agg32 + (size_t)(nbase + on) * 64));
        if (lane == 0) alpha_out[ei] = al;
      }
    }
  }
}

// ---------------- out[n,o] = relu(sum_d aggbf[n,d]*Wh[o,d]) -> fp32 (MFMA) ----------------
__global__ __launch_bounds__(256) void out_gemm_bf(
    const float* __restrict__ Wh, const short* __restrict__ aggb,
    float* __restrict__ out) {
  int lane = threadIdx.x & 63;
  int lr = lane & 15, lg = lane >> 4;
  int gw = (blockIdx.x * blockDim.x + threadIdx.x) >> 6;
  int nwv = (gridDim.x * blockDim.x) >> 6;

  short8_t b[8][4];
#pragma unroll
  for (int ot = 0; ot < 8; ++ot)
#pragma unroll
    for (int kt = 0; kt < 4; ++kt) {
      const float* wp = Wh + (size_t)(ot * 16 + lr) * DIM + kt * 32 + lg * 8;
      b[ot][kt] = pack8(*(const float4*)wp, *(const float4*)(wp + 4));
    }

  for (int t = gw; t < N_NODES / 16; t += nwv) {
    const short* ap = aggb + ((size_t)t * 16 + lr) * DIM;
    short8_t a[4];
#pragma unroll
    for (int kt = 0; kt < 4; ++kt)
      a[kt] = *(const short8_t*)(ap + kt * 32 + lg * 8);
    f32x4 acc[8];
#pragma unroll
    for (int ot = 0; ot < 8; ++ot) {
      acc[ot] = (f32x4){0.f, 0.f, 0.f, 0.f};
#pragma unroll
      for (int kt = 0; kt < 4; ++kt)
        acc[ot] = __builtin_amdgcn_mfma_f32_16x16x32_bf16(a[kt], b[ot][kt], acc[ot], 0, 0, 0);
    }
    float* op = out + (size_t)t * 16 * DIM;
#pragma unroll
    for (int ot = 0; ot < 8; ++ot)
#pragma unroll
      for (int r = 0; r < 4; ++r)
        op[(size_t)(lg * 4 + r) * DIM + ot * 16 + lr] = fmaxf(acc[ot][r], 0.f);
  }
}

// ================= SMALL-ws fallback (round-2 proven path) =================
__global__ __launch_bounds__(256) void tq_kernel(
    const float* __restrict__ qemb, const float* __restrict__ Wq,
    float* __restrict__ Tq) {
  int t = blockIdx.x * 256 + threadIdx.x;
  if (t >= NQ * AA) return;
  int q = t >> 6, a = t & 63;
  float s = 0.f;
#pragma unroll 4
  for (int d = 0; d < DIM; ++d) s += qemb[q * DIM + d] * Wq[a * DIM + d];
  Tq[t] = s;
}

__global__ __launch_bounds__(256) void build_C_old(
    const float* __restrict__ qemb, const float* __restrict__ rela,
    const float* __restrict__ Wr, const float* __restrict__ Wqr,
    const float* __restrict__ Wsb, const float* __restrict__ Tq,
    __hip_bfloat16* __restrict__ Cout) {
  __shared__ float hrq[64 * 129];
  __shared__ float wqrT[128 * 65];
  __shared__ float wrT[128 * 65];
  __shared__ float hr_s[128];
  __shared__ float tr_s[64];
  int rho = blockIdx.x;
  int t = threadIdx.x;
  if (t < 128) hr_s[t] = rela[rho * DIM + t];
  __syncthreads();
  for (int i = t; i < 64 * 128; i += 256) {
    int a = i >> 7, d = i & 127;
    hrq[a * 129 + d] = qemb[i] * hr_s[d];
    wqrT[d * 65 + a] = Wqr[i];
    wrT[d * 65 + a] = Wr[i];
  }
  __syncthreads();
  if (t < 64) {
    float s = 0.f;
#pragma unroll 4
    for (int d = 0; d < DIM; ++d) s += wrT[d * 65 + t] * hr_s[d];
    tr_s[t] = s + Wsb[t];
  }
  __syncthreads();
  int qg = t >> 4, ag = t & 15;
  int q0 = qg * 4, a0 = ag * 4;
  float acc[4][4];
#pragma unroll
  for (int i = 0; i < 4; ++i)
#pragma unroll
    for (int j = 0; j < 4; ++j) acc[i][j] = 0.f;
  for (int d = 0; d < DIM; ++d) {
    float hv[4], wv[4];
#pragma unroll
    for (int i = 0; i < 4; ++i) hv[i] = hrq[(q0 + i) * 129 + d];
#pragma unroll
    for (int j = 0; j < 4; ++j) wv[j] = wqrT[d * 65 + a0 + j];
#pragma unroll
    for (int i = 0; i < 4; ++i)
#pragma unroll
      for (int j = 0; j < 4; ++j) acc[i][j] += hv[i] * wv[j];
  }
#pragma unroll
  for (int i = 0; i < 4; ++i)
#pragma unroll
    for (int j = 0; j < 4; ++j) {
      int q = q0 + i, a = a0 + j;
      Cout[(rho * 64 + q) * 64 + a] = __float2bfloat16(acc[i][j] + Tq[q * 64 + a] + tr_s[a]);
    }
}

__global__ __launch_bounds__(256) void build_S_old(
    const float* __restrict__ hidden, const float* __restrict__ Ws,
    __hip_bfloat16* __restrict__ Sout) {
  int lane = threadIdx.x & 63;
  int lr = lane & 15, lg = lane >> 4;
  int gw = (blockIdx.x * blockDim.x + threadIdx.x) >> 6;
  int nwv = (gridDim.x * blockDim.x) >> 6;
  short8_t b[4][4];
#pragma unroll
  for (int ot = 0; ot < 4; ++ot)
#pragma unroll
    for (int kt = 0; kt < 4; ++kt) {
      const float* wp = Ws + (size_t)(ot * 16 + lr) * DIM + kt * 32 + lg * 8;
      b[ot][kt] = pack8(*(const float4*)wp, *(const float4*)(wp + 4));
    }
  for (int t = gw; t < N_NODES / 16; t += nwv) {
    const float* ap = hidden + (size_t)t * 16 * DIM + (size_t)lr * DIM;
    short8_t a[4];
#pragma unroll
    for (int kt = 0; kt < 4; ++kt) {
      const float* p = ap + kt * 32 + lg * 8;
      a[kt] = pack8(*(const float4*)p, *(const float4*)(p + 4));
    }
    f32x4 acc[4];
#pragma unroll
    for (int ot = 0; ot < 4; ++ot) {
      acc[ot] = (f32x4){0.f, 0.f, 0.f, 0.f};
#pragma unroll
      for (int kt = 0; kt < 4; ++kt)
        acc[ot] = __builtin_amdgcn_mfma_f32_16x16x32_bf16(a[kt], b[ot][kt], acc[ot], 0, 0, 0);
    }
#pragma unroll
    for (int ot = 0; ot < 4; ++ot)
#pragma unroll
      for (int r = 0; r < 4; ++r)
        Sout[((size_t)t * 16 + lg * 4 + r) * 64 + ot * 16 + lr] = __float2bfloat16(acc[ot][r]);
  }
}

__global__ __launch_bounds__(256) void edge_kernel_old(
    const float* __restrict__ hidden, const float* __restrict__ rela,
    const __hip_bfloat16* __restrict__ S, const __hip_bfloat16* __restrict__ C,
    const float* __restrict__ wal, const float* __restrict__ walb,
    const int* __restrict__ ridx, const int* __restrict__ rel,
    const int* __restrict__ sub, const int* __restrict__ obj,
    float* __restrict__ agg, float* __restrict__ alpha_out) {
  int lane = threadIdx.x & 63;
  int wid = (blockIdx.x * blockDim.x + threadIdx.x) >> 6;
  const int CH = 124;
  int e0 = wid * CH;
  if (e0 >= N_EDGES) return;
  int e1 = e0 + CH;
  if (e1 > N_EDGES) e1 = N_EDGES;
  float wa = wal[lane];
  float wb = walb[0];
  for (int e = e0; e < e1; e += 4) {
    int4 ss = *(const int4*)(sub + e);
    int4 rr = *(const int4*)(rel + e);
    int4 qq = *(const int4*)(ridx + e);
    int4 oo = *(const int4*)(obj + e);
    int s[4] = {ss.x, ss.y, ss.z, ss.w};
    int r[4] = {rr.x, rr.y, rr.z, rr.w};
    int q[4] = {qq.x, qq.y, qq.z, qq.w};
    int o[4] = {oo.x, oo.y, oo.z, oo.w};
    float y[4];
#pragma unroll
    for (int u = 0; u < 4; ++u) {
      float x = __bfloat162float(S[(size_t)s[u] * 64 + lane]) +
                __bfloat162float(C[((size_t)r[u] * 64 + q[u]) * 64 + lane]);
      y[u] = fmaxf(x, 0.f) * wa;
    }
    float h0[4], h1[4], r0[4], r1[4];
#pragma unroll
    for (int u = 0; u < 4; ++u) {
      h0[u] = hidden[(size_t)s[u] * DIM + lane];
      h1[u] = hidden[(size_t)s[u] * DIM + 64 + lane];
      r0[u] = rela[(size_t)r[u] * DIM + lane];
      r1[u] = rela[(size_t)r[u] * DIM + 64 + lane];
    }
#pragma unroll
    for (int off = 32; off; off >>= 1) {
#pragma unroll
      for (int u = 0; u < 4; ++u) y[u] += __shfl_xor(y[u], off);
    }
    float al[4];
#pragma unroll
    for (int u = 0; u < 4; ++u) al[u] = 1.f / (1.f + __expf(-(y[u] + wb)));
#pragma unroll
    for (int u = 0; u < 4; ++u) {
      unsafeAtomicAdd(&agg[(size_t)o[u] * DIM + lane], al[u] * h0[u] * r0[u]);
      unsafeAtomicAdd(&agg[(size_t)o[u] * DIM + 64 + lane], al[u] * h1[u] * r1[u]);
    }
    if (lane == 0)
      *(float4*)(alpha_out + e) = make_float4(al[0], al[1], al[2], al[3]);
  }
}

__global__ __launch_bounds__(256) void out_gemm_old(
    const float* __restrict__ Wh, float* __restrict__ agg) {
  int lane = threadIdx.x & 63;
  int lr = lane & 15, lg = lane >> 4;
  int gw = (blockIdx.x * blockDim.x + threadIdx.x) >> 6;
  int nwv = (gridDim.x * blockDim.x) >> 6;
  short8_t b[8][4];
#pragma unroll
  for (int ot = 0; ot < 8; ++ot)
#pragma unroll
    for (int kt = 0; kt < 4; ++kt) {
      const float* wp = Wh + (size_t)(ot * 16 + lr) * DIM + kt * 32 + lg * 8;
      b[ot][kt] = pack8(*(const float4*)wp, *(const float4*)(wp + 4));
    }
  for (int t = gw; t < N_NODES / 16; t += nwv) {
    float* ap = agg + (size_t)t * 16 * DIM + (size_t)lr * DIM;
    short8_t a[4];
#pragma unroll
    for (int kt = 0; kt < 4; ++kt) {
      const float* p = ap + kt * 32 + lg * 8;
      a[kt] = pack8(*(const float4*)p, *(const float4*)(p + 4));
    }
    f32x4 acc[8];
#pragma unroll
    for (int ot = 0; ot < 8; ++ot) {
      acc[ot] = (f32x4){0.f, 0.f, 0.f, 0.f};
#pragma unroll
      for (int kt = 0; kt < 4; ++kt)
        acc[ot] = __builtin_amdgcn_mfma_f32_16x16x32_bf16(a[kt], b[ot][kt], acc[ot], 0, 0, 0);
    }
    float* op = agg + (size_t)t * 16 * DIM;
#pragma unroll
    for (int ot = 0; ot < 8; ++ot)
#pragma unroll
      for (int r = 0; r < 4; ++r)
        op[(size_t)(lg * 4 + r) * DIM + ot * 16 + lr] = fmaxf(acc[ot][r], 0.f);
  }
}

extern "C" void kernel_launch(void* const* d_in, const int* in_sizes, int n_in,
                              void* d_out, int out_size, void* d_ws, size_t ws_size,
                              hipStream_t stream) {
  const float* hidden = (const float*)d_in[0];
  const float* qemb   = (const float*)d_in[1];
  const float* rela   = (const float*)d_in[2];
  const float* Ws_w   = (const float*)d_in[3];
  const float* Ws_b   = (const float*)d_in[4];
  const float* Wr_w   = (const float*)d_in[5];
  const float* Wq_w   = (const float*)d_in[6];
  const float* Wqr_w  = (const float*)d_in[7];
  const float* wal_w  = (const float*)d_in[8];
  const float* wal_b  = (const float*)d_in[9];
  const float* Wh_w   = (const float*)d_in[10];
  const int* r_idx    = (const int*)d_in[11];
  const int* rel      = (const int*)d_in[12];
  const int* sub      = (const int*)d_in[13];
  const int* obj      = (const int*)d_in[14];

  float* out_hidden = (float*)d_out;
  float* out_alpha  = out_hidden + (size_t)N_NODES * DIM;

  char* ws = (char*)d_ws;
  const size_t OFF_C8  = 0;
  const size_t SZ_C8   = (size_t)NRELR * 64 * 64;     // 1,642,496
  const size_t OFF_S8  = OFF_C8 + SZ_C8;
  const size_t SZ_S8   = (size_t)N_NODES * 64;        // 12,800,000
  const size_t OFF_RB  = OFF_S8 + SZ_S8;              // 14,442,496
  const size_t SZ_RB   = (size_t)NRELR * DIM * 2;     // 102,656
  const size_t OFF_HB  = OFF_RB + SZ_RB;              // 14,545,152
  const size_t SZ_HB   = (size_t)N_NODES * DIM * 2;   // 51,200,000
  const size_t OFF_AG  = OFF_HB + SZ_HB;              // 65,745,152
  const size_t OFF_H2D = OFF_AG + SZ_HB;              // 116,945,152

  // choose znum tier by available ws
  int znum = 0;
  size_t off_o2d = 0, off_tot = 0, off_base = 0, off_rec = 0;
  for (int zc = 256; zc >= 128; zc >>= 1) {
    size_t szh = (size_t)zc * NBK * 4;
    size_t o2d = OFF_H2D + szh;
    size_t tot = o2d + szh;
    size_t bas = tot + 16384;
    size_t rec = bas + 16384;
    size_t need = rec + (size_t)N_EDGES * 8;
    if (ws_size >= need) {
      znum = zc; off_o2d = o2d; off_tot = tot; off_base = bas; off_rec = rec;
      break;
    }
  }

  if (znum) {
    unsigned char* C8 = (unsigned char*)(ws + OFF_C8);
    unsigned char* S8 = (unsigned char*)(ws + OFF_S8);
    unsigned short* relab = (unsigned short*)(ws + OFF_RB);
    short* hidb = (short*)(ws + OFF_HB);
    unsigned short* aggb = (unsigned short*)(ws + OFF_AG);
    int* hist2d = (int*)(ws + OFF_H2D);
    int* off2d  = (int*)(ws + off_o2d);
    int* totals = (int*)(ws + off_tot);
    int* base   = (int*)(ws + off_base);
    uint2* recs = (uint2*)(ws + off_rec);

    prep_kernel<<<CBK + SBK + znum, 256, 0, stream>>>(
        hidden, qemb, rela, Ws_w, Ws_b, Wr_w, Wq_w, Wqr_w, obj,
        C8, S8, relab, hidb, hist2d, znum);
    offsetsB_kernel<<<(NBK + 3) / 4, 256, 0, stream>>>(hist2d, off2d, totals, znum);
    scan_kernel<<<1, 256, 0, stream>>>(totals, base);
    scatter3_kernel<<<znum, 256, 0, stream>>>(r_idx, rel, sub, obj, base, off2d, recs, znum);
    bucket2_kernel<<<NBK, 256, 0, stream>>>(
        (const unsigned*)hidb, (const unsigned*)relab, S8, C8,
        wal_w, wal_b, base, recs, (unsigned*)aggb, out_alpha);
    out_gemm_bf<<<512, 256, 0, stream>>>(Wh_w, (const short*)aggb, out_hidden);
  } else {
    // SMALL fallback: round-2 proven path (28.9 MB)
    const size_t OFF_CBo = 16384;
    const size_t SZ_CBo  = (size_t)NRELR * 64 * 64 * 2;
    const size_t OFF_SBo = OFF_CBo + SZ_CBo;
    float* Tq = (float*)ws;
    __hip_bfloat16* Cb = (__hip_bfloat16*)(ws + OFF_CBo);
    __hip_bfloat16* Sb = (__hip_bfloat16*)(ws + OFF_SBo);
    hipMemsetAsync(out_hidden, 0, (size_t)N_NODES * DIM * sizeof(float), stream);
    tq_kernel<<<16, 256, 0, stream>>>(qemb, Wq_w, Tq);
    build_C_old<<<NRELR, 256, 0, stream>>>(qemb, rela, Wr_w, Wqr_w, Ws_b, Tq, Cb);
    build_S_old<<<512, 256, 0, stream>>>(hidden, Ws_w, Sb);
    edge_kernel_old<<<2048, 256, 0, stream>>>(hidden, rela, Sb, Cb, wal_w, wal_b,
                                              r_idx, rel, sub, obj, out_hidden, out_alpha);
    out_gemm_old<<<512, 256, 0, stream>>>(Wh_w, out_hidden);
  }
}